// Round 7
// baseline (178.906 us; speedup 1.0000x reference)
//
#include <hip/hip_runtime.h>
#include <hip/hip_fp16.h>

typedef _Float16 half_t;
typedef __attribute__((ext_vector_type(2))) _Float16 f16x2;
typedef __attribute__((ext_vector_type(4))) _Float16 f16x4;
typedef __attribute__((ext_vector_type(8))) _Float16 f16x8;
typedef __attribute__((ext_vector_type(4))) float f32x4;

// ---------------------------------------------------------------------------
// Separable MLP: h = relu(z[src].W1a + z[dst].W1b + b1) ; out = h.W2 + b2
// R7: gemm latency attack. gemm ~23 us vs 15.9 floor; R6 showed the residual
//   isn't request-count. Theory: staging waits on z-loads issued only ~350cy
//   earlier (< ~900cy HBM latency) -> per-iter vmcnt stall.
//   (a) depth-2 register prefetch: hold tiles t+1 (p) and t+2 (q) in f32
//       regs; loads get ~2 iters of slack. LDS dbuf + 1 barrier/iter same.
//   (b) launch_bounds(256,4) + grid 1024: force <=128 VGPR -> 4 blocks/CU
//       (16 waves/CU) for TLP. Revert both if spill/regression.
// Edge phase FROZEN: 73.4 us across R0/R4/R5/R6; fabric random-gather
//   ceiling ~3.4 TB/s at 240 MB L2-miss. R1 (deeper pipe, nt) regressed.
//   1D src-sort re-derived and rejected: permutation scatter (sorted triples
//   + out unpermute, cross-XCD partial lines) costs ~= locality gain.
// Fixed harness overhead (fillBuffer re-poison): ~75 us/replay, not ours.
// Structure: prep_w1 (2 us) -> gemm_all (LDS-A dbuf + register-B) -> edge.
// Y row layout (256 f16): position p holds hidden index
//   n(p) = ((p>>6)*4 + (p&3))*16 + ((p>>2)&15) per 128-half; b1/W2 permuted
//   identically in edge (edge math positional; any bijection works).
// ---------------------------------------------------------------------------

// Micro-prep: W1 -> f16 B-fragment blob (64 KB), 128 blocks.
// B-fragment (ks 0..3, nt 0..15): lane L elem j holds
//   B[k = ks*32 + (L>>4)*8 + j][ncol = nt*16 + (L&15)]
// where B[k][ncol] = W1[(ncol<128 ? k : 128+k)][ncol & 127].
// Flat f16 index t = ((ks*16 + nt)*64 + L)*8 + j.
__global__ void prep_w1_kernel(const float* __restrict__ W1,
                               half_t* __restrict__ w1s) {
    const int t = blockIdx.x * 256 + threadIdx.x;   // 0..32767
    const int j  = t & 7;
    const int L  = (t >> 3) & 63;
    const int nt = (t >> 9) & 15;
    const int ks = t >> 13;
    const int k    = ks * 32 + (L >> 4) * 8 + j;
    const int ncol = nt * 16 + (L & 15);
    const int row  = (ncol < 128) ? k : 128 + k;
    w1s[t] = (half_t)W1[row * 128 + (ncol & 127)];
}

static __device__ __forceinline__ f16x8 cvt8(const float4& a, const float4& b) {
    f16x8 w;
    w[0] = (_Float16)a.x; w[1] = (_Float16)a.y;
    w[2] = (_Float16)a.z; w[3] = (_Float16)a.w;
    w[4] = (_Float16)b.x; w[5] = (_Float16)b.y;
    w[6] = (_Float16)b.z; w[7] = (_Float16)b.w;
    return w;
}

// Fused gemm: Y[node] = [z@W1a | z@W1b] in f16, A staged through LDS.
// Block = 4 waves; wave wq owns 64 output cols (B quarter in 64 VGPRs from
// w1s blob). Per iter: issue tile t+2 loads FIRST (depth-2), compute tile t
// from LDS (4 ds_read_b128 + 16 MFMA + 4 f16x4 stores), then cvt+stage tile
// t+1 (its loads got ~2 iters of slack). One barrier per iter.
// LDS layout (per 4KB buf): elem(r, c) at f16 index
//   r*128 + ((c/8) ^ (r&7))*8 + (c&7),  r=0..15, c=0..127.
__global__ __launch_bounds__(256, 4)
void gemm_all_kernel(const float* __restrict__ z,
                     const half_t* __restrict__ w1s,
                     half_t* __restrict__ Y,
                     int n_groups, int stride_groups) {
    __shared__ __align__(16) half_t abuf[2][2048];   // 2 x 4 KB

    const int tid  = threadIdx.x;
    const int wq   = tid >> 6;           // wave's column-quarter, 0..3
    const int lane = tid & 63;
    const int nlo  = lane & 15;
    const int quad = lane >> 4;

    // B quarter in registers (16 KB/wave) from prebuilt blob (R3-proven).
    const f16x8* blob = reinterpret_cast<const f16x8*>(w1s);
    f16x8 breg[4][4];                    // [ks][ntp]
#pragma unroll
    for (int ks = 0; ks < 4; ++ks)
#pragma unroll
        for (int ntp = 0; ntp < 4; ++ntp)
            breg[ks][ntp] = blob[(ks * 16 + wq * 4 + ntp) * 64 + lane];

    // Staging role: row sr = tid>>4 (contiguous-row coalescing, R6),
    // col-chunk sslot = tid&15.
    const int sr    = tid >> 4;
    const int sslot = tid & 15;
    const int swz_w = (sslot ^ (sr & 7)) * 8 + sr * 128;  // f16 idx in buf
    // Frag-read offsets: row nlo, slots quad + 4*ks:
    //   f16 idx = nlo*128 + ((quad + 4*ks) ^ (nlo&7))*8.

    int g = blockIdx.x;                  // grid = 1024 <= n_groups always
    const int S = stride_groups;

    // Prologue: stage tile g into buf0 directly.
    {
        const float4* ap = reinterpret_cast<const float4*>(
            z + ((size_t)(g * 16 + sr) * 128) + sslot * 8);
        *reinterpret_cast<f16x8*>(&abuf[0][swz_w]) = cvt8(ap[0], ap[1]);
    }
    // p = in-flight f32 data for tile g+S.
    int g1 = g + S; if (g1 >= n_groups) g1 = g;
    const float4* ap1 = reinterpret_cast<const float4*>(
        z + ((size_t)(g1 * 16 + sr) * 128) + sslot * 8);
    float4 pa = ap1[0], pb = ap1[1];
    __syncthreads();

    int cur = 0;
    for (; g < n_groups; g += S) {
        // Issue tile t+2 loads first: ~2 full iterations of latency slack.
        int g2 = g + 2 * S; if (g2 >= n_groups) g2 = g;   // harmless re-read
        const float4* ap2 = reinterpret_cast<const float4*>(
            z + ((size_t)(g2 * 16 + sr) * 128) + sslot * 8);
        const float4 qa = ap2[0], qb = ap2[1];

        // A fragments from LDS (swizzled, uniform bank spread).
        f16x8 av[4];
#pragma unroll
        for (int ks = 0; ks < 4; ++ks)
            av[ks] = *reinterpret_cast<const f16x8*>(
                &abuf[cur][nlo * 128 + (((quad + 4 * ks) ^ (nlo & 7)) << 3)]);

        f32x4 acc[4];
#pragma unroll
        for (int ntp = 0; ntp < 4; ++ntp)
            acc[ntp] = (f32x4){0.f, 0.f, 0.f, 0.f};

#pragma unroll
        for (int ks = 0; ks < 4; ++ks)
#pragma unroll
            for (int ntp = 0; ntp < 4; ++ntp)
                acc[ntp] = __builtin_amdgcn_mfma_f32_16x16x32_f16(
                    av[ks], breg[ks][ntp], acc[ntp], 0, 0, 0);

        // C/D: row m = quad*4 + r, col = (wq*4+ntp)*16 + nlo.
        // f16x4 store at p = wq*64 + nlo*4 + j  =>  n(p) as in header.
#pragma unroll
        for (int r = 0; r < 4; ++r) {
            const int nr = g * 16 + quad * 4 + r;
            f16x4 o;
#pragma unroll
            for (int j = 0; j < 4; ++j) o[j] = (_Float16)acc[j][r];
            *reinterpret_cast<f16x4*>(Y + (size_t)nr * 256 + wq * 64 +
                                      nlo * 4) = o;
        }

        // Stage tile t+1 (p was issued at the top of the PREVIOUS iter).
        *reinterpret_cast<f16x8*>(&abuf[cur ^ 1][swz_w]) = cvt8(pa, pb);
        __syncthreads();   // separates this write from next iter's reads AND
                           // this iter's reads from next iter's write.
        cur ^= 1;
        pa = qa; pb = qb;  // shift pipeline
    }
}

static __device__ __forceinline__ f16x2 pair2(const f16x8& v, int p) {
    f16x2 r; r[0] = v[2 * p]; r[1] = v[2 * p + 1]; return r;
}

// Edge phase: 16 lanes per edge (4 edges/wave/iter), coalesced 256-B segment
// gathers. Three-deep pipeline: gathers issued 2 iters ahead, indices 3.
// FROZEN at R0 config (fabric-bound; R1 probes regressed).
__global__ __launch_bounds__(256, 8)
void edge_decode_kernel(const half_t* __restrict__ Y,
                        const int* __restrict__ es,
                        const int* __restrict__ ed,
                        const float* __restrict__ b1,
                        const float* __restrict__ W2,
                        const float* __restrict__ b2,
                        float* __restrict__ out,
                        int n_e, int stride_e) {
    __shared__ __align__(16) half_t b1h[128];
    __shared__ __align__(16) half_t w2h[128];
    if (threadIdx.x < 128) {
        const int i = threadIdx.x;
        // position i holds hidden index n(i) (per 128-half):
        const int n = (((i >> 6) << 2) + (i & 3)) * 16 + ((i >> 2) & 15);
        b1h[i] = (half_t)b1[n];
        w2h[i] = (half_t)W2[n];
    }
    __syncthreads();

    const int lane  = threadIdx.x & 63;
    const int sl    = lane & 15;    // 16-B slice within the 256-B half-row
    const int eslot = lane >> 4;    // which of the wave's 4 edges
    const f16x8 bv = reinterpret_cast<const f16x8*>(b1h)[sl];
    const f16x8 wv = reinterpret_cast<const f16x8*>(w2h)[sl];
    const float b2v = b2[0];
    const f16x2 zero2 = {(_Float16)0, (_Float16)0};

    const int w = blockIdx.x * 4 + (threadIdx.x >> 6);
    int e0 = w * 4;
    if (e0 >= n_e) return;

    // iter-0 gathers
    int ec = e0 + eslot; if (ec >= n_e) ec = 0;
    int sa = es[ec], da = ed[ec];
    f16x8 u0 = *reinterpret_cast<const f16x8*>(Y + (size_t)sa * 256 + sl * 8);
    f16x8 v0 = *reinterpret_cast<const f16x8*>(Y + (size_t)da * 256 + 128 +
                                               sl * 8);
    // iter-1 gathers
    ec = e0 + stride_e + eslot; if (ec >= n_e) ec = 0;
    sa = es[ec]; da = ed[ec];
    f16x8 u1 = *reinterpret_cast<const f16x8*>(Y + (size_t)sa * 256 + sl * 8);
    f16x8 v1 = *reinterpret_cast<const f16x8*>(Y + (size_t)da * 256 + 128 +
                                               sl * 8);
    // iter-2 indices
    ec = e0 + 2 * stride_e + eslot; if (ec >= n_e) ec = 0;
    int s2 = es[ec], d2 = ed[ec];

    for (; e0 < n_e; e0 += stride_e) {
        const int e = e0 + eslot;
        const bool valid = (e < n_e);

        // issue iter+2 gathers (consumed two iterations from now)
        const f16x8 u2 = *reinterpret_cast<const f16x8*>(
            Y + (size_t)s2 * 256 + sl * 8);
        const f16x8 v2 = *reinterpret_cast<const f16x8*>(
            Y + (size_t)d2 * 256 + 128 + sl * 8);

        // fetch indices three iterations ahead
        {
            int en = e0 + 3 * stride_e + eslot;
            if (en >= n_e) en = 0;
            s2 = es[en];
            d2 = ed[en];
        }

        float acc = 0.f;
#pragma unroll
        for (int p = 0; p < 4; ++p) {
            f16x2 h2 = pair2(u0, p) + pair2(v0, p) + pair2(bv, p);
            h2 = __builtin_elementwise_max(h2, zero2);
            acc = __builtin_amdgcn_fdot2(h2, pair2(wv, p), acc, false);
        }
        acc += __shfl_xor(acc, 1);
        acc += __shfl_xor(acc, 2);
        acc += __shfl_xor(acc, 4);
        acc += __shfl_xor(acc, 8);
        if (sl == 0 && valid) out[e] = acc + b2v;

        u0 = u1; v0 = v1;
        u1 = u2; v1 = v2;
    }
}

// Insurance fallback (only if workspace is unexpectedly tiny): correct, slow.
__global__ void naive_edge_kernel(const float* __restrict__ z,
                                  const int* __restrict__ eidx,
                                  const float* __restrict__ W1,
                                  const float* __restrict__ b1,
                                  const float* __restrict__ W2,
                                  const float* __restrict__ b2,
                                  float* __restrict__ out, int n_edges) {
    __shared__ float feat[256];
    __shared__ float red[2];
    const int e = blockIdx.x;
    const int t = threadIdx.x;           // 128 threads
    const int s = eidx[e], d = eidx[n_edges + e];
    feat[t] = z[(size_t)s * 128 + t];
    feat[128 + t] = z[(size_t)d * 128 + t];
    __syncthreads();
    float h = b1[t];
    for (int k = 0; k < 256; ++k) h = fmaf(feat[k], W1[k * 128 + t], h);
    float p = fmaxf(h, 0.f) * W2[t];
    for (int off = 32; off; off >>= 1) p += __shfl_down(p, off);
    if ((t & 63) == 0) red[t >> 6] = p;
    __syncthreads();
    if (t == 0) out[e] = red[0] + red[1] + b2[0];
}

extern "C" void kernel_launch(void* const* d_in, const int* in_sizes, int n_in,
                              void* d_out, int out_size, void* d_ws,
                              size_t ws_size, hipStream_t stream) {
    const float* z   = (const float*)d_in[0];
    const int* eidx  = (const int*)d_in[1];   // int64 ref passed as int32
    const float* W1  = (const float*)d_in[2];
    const float* b1  = (const float*)d_in[3];
    const float* W2  = (const float*)d_in[4];
    const float* b2  = (const float*)d_in[5];
    float* out       = (float*)d_out;

    const int nz      = in_sizes[0];          // 12,800,000
    const int n_nodes = nz / 128;             // 100,000
    const int n_edges = in_sizes[1] / 2;      // 1,000,000

    const size_t Y_bytes   = (size_t)n_nodes * 256 * sizeof(half_t); // 51.2 MB
    const size_t w1s_bytes = 32768 * sizeof(half_t);                 // 64 KB

    if (ws_size >= Y_bytes + w1s_bytes) {
        half_t* Y   = (half_t*)d_ws;
        half_t* w1s = (half_t*)((char*)d_ws + Y_bytes);

        prep_w1_kernel<<<128, 256, 0, stream>>>(W1, w1s);

        const int n_groups = n_nodes / 16;          // 6250 exact
        const int gblocks  = 1024;                  // 4 blocks/CU residency
        gemm_all_kernel<<<gblocks, 256, 0, stream>>>(z, w1s, Y, n_groups,
                                                     gblocks);

        const int eblocks  = 2048;                  // 8 blocks/CU -> 32 w/CU
        const int stride_e = eblocks * 4 * 4;       // 32768
        edge_decode_kernel<<<eblocks, 256, 0, stream>>>(
            Y, eidx, eidx + n_edges, b1, W2, b2, out, n_edges, stride_e);
    } else {
        naive_edge_kernel<<<n_edges, 128, 0, stream>>>(z, eidx, W1, b1, W2, b2,
                                                       out, n_edges);
    }
}

// Round 8
// 176.140 us; speedup vs baseline: 1.0157x; 1.0157x over previous
//
#include <hip/hip_runtime.h>
#include <hip/hip_fp16.h>

typedef _Float16 half_t;
typedef __attribute__((ext_vector_type(2))) _Float16 f16x2;
typedef __attribute__((ext_vector_type(4))) _Float16 f16x4;
typedef __attribute__((ext_vector_type(8))) _Float16 f16x8;
typedef __attribute__((ext_vector_type(4))) float f32x4;

// ---------------------------------------------------------------------------
// Separable MLP: h = relu(z[src].W1a + z[dst].W1b + b1) ; out = h.W2 + b2
// R8: REVERT to R6 exactly (best measured: 176.4 us). R7's depth-2 prefetch
//   + launch_bounds(256,4)/grid-1024 regressed to 178.9 (register pressure
//   at the forced 128-VGPR cap + per-block fixed costs at 6 iters/block).
// Final accounting (8 measurements):
//   ~75 us  harness fillBuffer re-poison (fixed, not ours)
//   ~73.4   edge_decode — rigid across R0/R4/R5/R6/R7; random-gather fabric
//           ceiling (~3.4 TB/s, 240 MB L2-miss of 512 MB demand). Deeper
//           pipeline (R1), nt hints (R1), splits (R2) all neutral/negative.
//   ~23     gemm_all — 100 MB stream floor is 15.9; residue = barrier +
//           prologue + occupancy overhead; R7 attempt to close it failed.
//   ~2      prep_w1; plus ~3 launch slack.
// Structure: prep_w1 -> gemm_all (LDS-A dbuf + register-B) -> edge_decode.
// Y row layout (256 f16): position p holds hidden index
//   n(p) = ((p>>6)*4 + (p&3))*16 + ((p>>2)&15) per 128-half; b1/W2 permuted
//   identically in edge (edge math positional; any bijection works).
// ---------------------------------------------------------------------------

// Micro-prep: W1 -> f16 B-fragment blob (64 KB), 128 blocks.
// B-fragment (ks 0..3, nt 0..15): lane L elem j holds
//   B[k = ks*32 + (L>>4)*8 + j][ncol = nt*16 + (L&15)]
// where B[k][ncol] = W1[(ncol<128 ? k : 128+k)][ncol & 127].
// Flat f16 index t = ((ks*16 + nt)*64 + L)*8 + j.
__global__ void prep_w1_kernel(const float* __restrict__ W1,
                               half_t* __restrict__ w1s) {
    const int t = blockIdx.x * 256 + threadIdx.x;   // 0..32767
    const int j  = t & 7;
    const int L  = (t >> 3) & 63;
    const int nt = (t >> 9) & 15;
    const int ks = t >> 13;
    const int k    = ks * 32 + (L >> 4) * 8 + j;
    const int ncol = nt * 16 + (L & 15);
    const int row  = (ncol < 128) ? k : 128 + k;
    w1s[t] = (half_t)W1[row * 128 + (ncol & 127)];
}

// Fused gemm: Y[node] = [z@W1a | z@W1b] in f16, A staged through LDS.
// Block = 4 waves; wave wq owns 64 output cols (B quarter in 64 VGPRs from
// w1s blob). Per iter: all 256 threads cvt-stage next A-tile (2 float4 loads
// + ds_write_b128), each wave ds_reads its 4 A-frags + 16 MFMA + 4 f16x4
// stores. One barrier per iter (write target = buffer read LAST iter).
// LDS layout (per 4KB buf): elem(r, c) at f16 index
//   r*128 + ((c/8) ^ (r&7))*8 + (c&7),  r=0..15, c=0..127.
__global__ __launch_bounds__(256, 3)
void gemm_all_kernel(const float* __restrict__ z,
                     const half_t* __restrict__ w1s,
                     half_t* __restrict__ Y,
                     int n_groups, int stride_groups) {
    __shared__ __align__(16) half_t abuf[2][2048];   // 2 x 4 KB

    const int tid  = threadIdx.x;
    const int wq   = tid >> 6;           // wave's column-quarter, 0..3
    const int lane = tid & 63;
    const int nlo  = lane & 15;
    const int quad = lane >> 4;

    // B quarter in registers (16 KB/wave) from prebuilt blob (R3-proven).
    const f16x8* blob = reinterpret_cast<const f16x8*>(w1s);
    f16x8 breg[4][4];                    // [ks][ntp]
#pragma unroll
    for (int ks = 0; ks < 4; ++ks)
#pragma unroll
        for (int ntp = 0; ntp < 4; ++ntp)
            breg[ks][ntp] = blob[(ks * 16 + wq * 4 + ntp) * 64 + lane];

    // Staging role: row sr (0..15), col-chunk sslot (0..15).
    // sr = tid>>4 -> a wave covers 4 CONTIGUOUS rows (4 x 1 KB dense
    // segments) instead of a 512-B-strided 16-line scatter (R6 fix).
    const int sr    = tid >> 4;
    const int sslot = tid & 15;
    const int swz_w = (sslot ^ (sr & 7)) * 8 + sr * 128;  // f16 idx in buf
    // Frag-read offsets: row nlo, slots quad + 4*ks.
    // f16 idx = nlo*128 + ((quad + 4*ks) ^ (nlo&7))*8.

    int g = blockIdx.x;                  // grid = 768 <= n_groups always

    // Prologue: stage A[g] into buf0.
    {
        const float4* ap = reinterpret_cast<const float4*>(
            z + ((size_t)(g * 16 + sr) * 128) + sslot * 8);
        const float4 a0 = ap[0];
        const float4 a1 = ap[1];
        f16x8 w;
        w[0] = (_Float16)a0.x; w[1] = (_Float16)a0.y;
        w[2] = (_Float16)a0.z; w[3] = (_Float16)a0.w;
        w[4] = (_Float16)a1.x; w[5] = (_Float16)a1.y;
        w[6] = (_Float16)a1.z; w[7] = (_Float16)a1.w;
        *reinterpret_cast<f16x8*>(&abuf[0][swz_w]) = w;
    }
    __syncthreads();

    int cur = 0;
    for (; g < n_groups; g += stride_groups) {
        // Issue next tile's global loads early (full MFMA block of slack).
        const int gn  = g + stride_groups;
        const int gpi = (gn < n_groups) ? gn : g;   // harmless re-read on last
        const float4* apn = reinterpret_cast<const float4*>(
            z + ((size_t)(gpi * 16 + sr) * 128) + sslot * 8);
        const float4 a0 = apn[0];
        const float4 a1 = apn[1];

        // A fragments from LDS (swizzled, uniform bank spread).
        f16x8 av[4];
#pragma unroll
        for (int ks = 0; ks < 4; ++ks)
            av[ks] = *reinterpret_cast<const f16x8*>(
                &abuf[cur][nlo * 128 + (((quad + 4 * ks) ^ (nlo & 7)) << 3)]);

        f32x4 acc[4];
#pragma unroll
        for (int ntp = 0; ntp < 4; ++ntp)
            acc[ntp] = (f32x4){0.f, 0.f, 0.f, 0.f};

#pragma unroll
        for (int ks = 0; ks < 4; ++ks)
#pragma unroll
            for (int ntp = 0; ntp < 4; ++ntp)
                acc[ntp] = __builtin_amdgcn_mfma_f32_16x16x32_f16(
                    av[ks], breg[ks][ntp], acc[ntp], 0, 0, 0);

        // C/D: row m = quad*4 + r, col = (wq*4+ntp)*16 + nlo.
        // f16x4 store at p = wq*64 + nlo*4 + j  =>  n(p) as in header.
#pragma unroll
        for (int r = 0; r < 4; ++r) {
            const int nr = g * 16 + quad * 4 + r;
            f16x4 o;
#pragma unroll
            for (int j = 0; j < 4; ++j) o[j] = (_Float16)acc[j][r];
            *reinterpret_cast<f16x4*>(Y + (size_t)nr * 256 + wq * 64 +
                                      nlo * 4) = o;
        }

        // Convert + stage next tile into the other buffer.
        {
            f16x8 w;
            w[0] = (_Float16)a0.x; w[1] = (_Float16)a0.y;
            w[2] = (_Float16)a0.z; w[3] = (_Float16)a0.w;
            w[4] = (_Float16)a1.x; w[5] = (_Float16)a1.y;
            w[6] = (_Float16)a1.z; w[7] = (_Float16)a1.w;
            *reinterpret_cast<f16x8*>(&abuf[cur ^ 1][swz_w]) = w;
        }
        __syncthreads();   // separates this write from next iter's reads AND
                           // this iter's reads from next iter's write.
        cur ^= 1;
    }
}

static __device__ __forceinline__ f16x2 pair2(const f16x8& v, int p) {
    f16x2 r; r[0] = v[2 * p]; r[1] = v[2 * p + 1]; return r;
}

// Edge phase: 16 lanes per edge (4 edges/wave/iter), coalesced 256-B segment
// gathers. Three-deep pipeline: gathers issued 2 iters ahead, indices 3.
// FROZEN at R0 config (fabric-bound; R1 probes regressed).
__global__ __launch_bounds__(256, 8)
void edge_decode_kernel(const half_t* __restrict__ Y,
                        const int* __restrict__ es,
                        const int* __restrict__ ed,
                        const float* __restrict__ b1,
                        const float* __restrict__ W2,
                        const float* __restrict__ b2,
                        float* __restrict__ out,
                        int n_e, int stride_e) {
    __shared__ __align__(16) half_t b1h[128];
    __shared__ __align__(16) half_t w2h[128];
    if (threadIdx.x < 128) {
        const int i = threadIdx.x;
        // position i holds hidden index n(i) (per 128-half):
        const int n = (((i >> 6) << 2) + (i & 3)) * 16 + ((i >> 2) & 15);
        b1h[i] = (half_t)b1[n];
        w2h[i] = (half_t)W2[n];
    }
    __syncthreads();

    const int lane  = threadIdx.x & 63;
    const int sl    = lane & 15;    // 16-B slice within the 256-B half-row
    const int eslot = lane >> 4;    // which of the wave's 4 edges
    const f16x8 bv = reinterpret_cast<const f16x8*>(b1h)[sl];
    const f16x8 wv = reinterpret_cast<const f16x8*>(w2h)[sl];
    const float b2v = b2[0];
    const f16x2 zero2 = {(_Float16)0, (_Float16)0};

    const int w = blockIdx.x * 4 + (threadIdx.x >> 6);
    int e0 = w * 4;
    if (e0 >= n_e) return;

    // iter-0 gathers
    int ec = e0 + eslot; if (ec >= n_e) ec = 0;
    int sa = es[ec], da = ed[ec];
    f16x8 u0 = *reinterpret_cast<const f16x8*>(Y + (size_t)sa * 256 + sl * 8);
    f16x8 v0 = *reinterpret_cast<const f16x8*>(Y + (size_t)da * 256 + 128 +
                                               sl * 8);
    // iter-1 gathers
    ec = e0 + stride_e + eslot; if (ec >= n_e) ec = 0;
    sa = es[ec]; da = ed[ec];
    f16x8 u1 = *reinterpret_cast<const f16x8*>(Y + (size_t)sa * 256 + sl * 8);
    f16x8 v1 = *reinterpret_cast<const f16x8*>(Y + (size_t)da * 256 + 128 +
                                               sl * 8);
    // iter-2 indices
    ec = e0 + 2 * stride_e + eslot; if (ec >= n_e) ec = 0;
    int s2 = es[ec], d2 = ed[ec];

    for (; e0 < n_e; e0 += stride_e) {
        const int e = e0 + eslot;
        const bool valid = (e < n_e);

        // issue iter+2 gathers (consumed two iterations from now)
        const f16x8 u2 = *reinterpret_cast<const f16x8*>(
            Y + (size_t)s2 * 256 + sl * 8);
        const f16x8 v2 = *reinterpret_cast<const f16x8*>(
            Y + (size_t)d2 * 256 + 128 + sl * 8);

        // fetch indices three iterations ahead
        {
            int en = e0 + 3 * stride_e + eslot;
            if (en >= n_e) en = 0;
            s2 = es[en];
            d2 = ed[en];
        }

        float acc = 0.f;
#pragma unroll
        for (int p = 0; p < 4; ++p) {
            f16x2 h2 = pair2(u0, p) + pair2(v0, p) + pair2(bv, p);
            h2 = __builtin_elementwise_max(h2, zero2);
            acc = __builtin_amdgcn_fdot2(h2, pair2(wv, p), acc, false);
        }
        acc += __shfl_xor(acc, 1);
        acc += __shfl_xor(acc, 2);
        acc += __shfl_xor(acc, 4);
        acc += __shfl_xor(acc, 8);
        if (sl == 0 && valid) out[e] = acc + b2v;

        u0 = u1; v0 = v1;
        u1 = u2; v1 = v2;
    }
}

// Insurance fallback (only if workspace is unexpectedly tiny): correct, slow.
__global__ void naive_edge_kernel(const float* __restrict__ z,
                                  const int* __restrict__ eidx,
                                  const float* __restrict__ W1,
                                  const float* __restrict__ b1,
                                  const float* __restrict__ W2,
                                  const float* __restrict__ b2,
                                  float* __restrict__ out, int n_edges) {
    __shared__ float feat[256];
    __shared__ float red[2];
    const int e = blockIdx.x;
    const int t = threadIdx.x;           // 128 threads
    const int s = eidx[e], d = eidx[n_edges + e];
    feat[t] = z[(size_t)s * 128 + t];
    feat[128 + t] = z[(size_t)d * 128 + t];
    __syncthreads();
    float h = b1[t];
    for (int k = 0; k < 256; ++k) h = fmaf(feat[k], W1[k * 128 + t], h);
    float p = fmaxf(h, 0.f) * W2[t];
    for (int off = 32; off; off >>= 1) p += __shfl_down(p, off);
    if ((t & 63) == 0) red[t >> 6] = p;
    __syncthreads();
    if (t == 0) out[e] = red[0] + red[1] + b2[0];
}

extern "C" void kernel_launch(void* const* d_in, const int* in_sizes, int n_in,
                              void* d_out, int out_size, void* d_ws,
                              size_t ws_size, hipStream_t stream) {
    const float* z   = (const float*)d_in[0];
    const int* eidx  = (const int*)d_in[1];   // int64 ref passed as int32
    const float* W1  = (const float*)d_in[2];
    const float* b1  = (const float*)d_in[3];
    const float* W2  = (const float*)d_in[4];
    const float* b2  = (const float*)d_in[5];
    float* out       = (float*)d_out;

    const int nz      = in_sizes[0];          // 12,800,000
    const int n_nodes = nz / 128;             // 100,000
    const int n_edges = in_sizes[1] / 2;      // 1,000,000

    const size_t Y_bytes   = (size_t)n_nodes * 256 * sizeof(half_t); // 51.2 MB
    const size_t w1s_bytes = 32768 * sizeof(half_t);                 // 64 KB

    if (ws_size >= Y_bytes + w1s_bytes) {
        half_t* Y   = (half_t*)d_ws;
        half_t* w1s = (half_t*)((char*)d_ws + Y_bytes);

        prep_w1_kernel<<<128, 256, 0, stream>>>(W1, w1s);

        const int n_groups = n_nodes / 16;          // 6250 exact
        const int gblocks  = 768;                   // 3 blocks/CU residency
        gemm_all_kernel<<<gblocks, 256, 0, stream>>>(z, w1s, Y, n_groups,
                                                     gblocks);

        const int eblocks  = 2048;                  // 8 blocks/CU -> 32 w/CU
        const int stride_e = eblocks * 4 * 4;       // 32768
        edge_decode_kernel<<<eblocks, 256, 0, stream>>>(
            Y, eidx, eidx + n_edges, b1, W2, b2, out, n_edges, stride_e);
    } else {
        naive_edge_kernel<<<n_edges, 128, 0, stream>>>(z, eidx, W1, b1, W2, b2,
                                                       out, n_edges);
    }
}